// Round 11
// baseline (56.943 us; speedup 1.0000x reference)
//
#include <hip/hip_runtime.h>
#include <hip/hip_fp16.h>

#define NF 39
#define NK 64
#define NRP (NF * NK / 2)   // 1248 row-pairs

__global__ __launch_bounds__(512, 4)   // VGPR cap 64 -> 32-wave band; LDS caps at 24 waves/CU
void deepfm_kernel(const int* __restrict__ feature,
                   const float* __restrict__ v_table,
                   const float* __restrict__ w_table,
                   const float* __restrict__ w0s,
                   const float* __restrict__ W0,
                   const float* __restrict__ b0,
                   const float* __restrict__ W1,
                   const float* __restrict__ b1,
                   const float* __restrict__ W2,
                   const float* __restrict__ b2,
                   const float* __restrict__ W3,
                   const float* __restrict__ b3,
                   float* __restrict__ out)
{
    // W0 as fp16 pairs over adjacent k: [j][rowpair], rp covers rows 2rp,2rp+1
    // (row = f*64 + k). Lane kq reads uint2 at [j][f*32 + 2*kq]: 16 lanes x 8B
    // contiguous = all 32 banks once; the 4 sample-groups broadcast. Conflict-free.
    __shared__ unsigned w0_lds[10 * NRP];   // 49920 B -> 3 blocks/CU by LDS

    for (int i = threadIdx.x; i < 10 * NRP; i += 512) {
        const int j  = i / NRP;
        const int rp = i - j * NRP;
        const __half lo = __float2half_rn(W0[(2 * rp)     * 10 + j]);
        const __half hi = __float2half_rn(W0[(2 * rp + 1) * 10 + j]);
        w0_lds[j * NRP + rp] = __builtin_bit_cast(unsigned, __halves2half2(lo, hi));
    }
    __syncthreads();

    const int lane = threadIdx.x & 63;
    const int wave = threadIdx.x >> 6;            // 0..7
    const int s0   = blockIdx.x * 32 + wave * 4;  // 4 samples per wave
    const int sg   = lane >> 4;                   // sample within wave (0..3)
    const int kq   = lane & 15;                   // k-quad: k = 4*kq .. 4*kq+3

    const int* fptr = feature + (size_t)(s0 + sg) * NF;   // per-lane, loop-invariant

    __half2 acc[10];              // packed even/odd-k layer-0 partials: 10 VGPRs total
    float sv[4], sq[4];
    float lin = 0.f;
    #pragma unroll
    for (int j = 0; j < 10; ++j) acc[j] = __builtin_bit_cast(__half2, 0u);
    #pragma unroll
    for (int i = 0; i < 4; ++i) { sv[i] = 0.f; sq[i] = 0.f; }

    #pragma unroll 2
    for (int f = 0; f < NF; ++f) {
        const int idx = fptr[f];                        // 16-lane dup, HW-merged
        lin += w_table[idx];                            // cache-resident gather
        // one wave-instruction fetches 4 full 256B rows (1KB in flight per instr)
        const float4 v4 = ((const float4*)(v_table + ((size_t)(unsigned)idx << 6)))[kq];
        sv[0] += v4.x;  sq[0] = fmaf(v4.x, v4.x, sq[0]);
        sv[1] += v4.y;  sq[1] = fmaf(v4.y, v4.y, sq[1]);
        sv[2] += v4.z;  sq[2] = fmaf(v4.z, v4.z, sq[2]);
        sv[3] += v4.w;  sq[3] = fmaf(v4.w, v4.w, sq[3]);

        const __half2 v01 = __builtin_bit_cast(__half2, __builtin_amdgcn_cvt_pkrtz(v4.x, v4.y));
        const __half2 v23 = __builtin_bit_cast(__half2, __builtin_amdgcn_cvt_pkrtz(v4.z, v4.w));
        const unsigned base = f * 32 + 2 * kq;
        #pragma unroll
        for (int j = 0; j < 10; ++j) {
            const uint2 u = *(const uint2*)&w0_lds[j * NRP + base];
            acc[j] = __hfma2(v01, __builtin_bit_cast(__half2, u.x), acc[j]);   // v_pk_fma_f16
            acc[j] = __hfma2(v23, __builtin_bit_cast(__half2, u.y), acc[j]);
        }
    }

    // FM term: fold k-slots, then 4-step butterfly across the 16-lane group
    float t = 0.f;
    #pragma unroll
    for (int i = 0; i < 4; ++i) t += fmaf(sv[i], sv[i], -sq[i]);
    float hj[10];
    #pragma unroll
    for (int j = 0; j < 10; ++j)
        hj[j] = __low2float(acc[j]) + __high2float(acc[j]);
    #pragma unroll
    for (int m = 1; m < 16; m <<= 1) {
        t += __shfl_xor(t, m, 64);
        #pragma unroll
        for (int j = 0; j < 10; ++j)
            hj[j] += __shfl_xor(hj[j], m, 64);
    }

    // tiny MLP tail (values uniform within group; computed redundantly)
    const float w0v = w0s[0];
    float h0v[10];
    #pragma unroll
    for (int j = 0; j < 10; ++j) h0v[j] = fmaxf(hj[j] + b0[j], 0.f);
    float h1[5];
    #pragma unroll
    for (int p = 0; p < 5; ++p) {
        float a = b1[p];
        #pragma unroll
        for (int j = 0; j < 10; ++j) a = fmaf(h0v[j], W1[j * 5 + p], a);
        h1[p] = fmaxf(a, 0.f);
    }
    float h2[3];
    #pragma unroll
    for (int q = 0; q < 3; ++q) {
        float a = b2[q];
        #pragma unroll
        for (int p = 0; p < 5; ++p) a = fmaf(h1[p], W2[p * 3 + q], a);
        h2[q] = fmaxf(a, 0.f);
    }
    float dnn = b3[0];
    #pragma unroll
    for (int q = 0; q < 3; ++q) dnn = fmaf(h2[q], W3[q], dnn);

    if (kq == 0) out[s0 + sg] = 0.5f * t + lin + w0v + dnn;
}

extern "C" void kernel_launch(void* const* d_in, const int* in_sizes, int n_in,
                              void* d_out, int out_size, void* d_ws, size_t ws_size,
                              hipStream_t stream) {
    const int*   feature = (const int*)  d_in[0];
    const float* v_table = (const float*)d_in[1];
    const float* w_table = (const float*)d_in[2];
    const float* w0s     = (const float*)d_in[3];
    const float* W0      = (const float*)d_in[4];
    const float* b0      = (const float*)d_in[5];
    const float* W1      = (const float*)d_in[6];
    const float* b1      = (const float*)d_in[7];
    const float* W2      = (const float*)d_in[8];
    const float* b2      = (const float*)d_in[9];
    const float* W3      = (const float*)d_in[10];
    const float* b3      = (const float*)d_in[11];

    deepfm_kernel<<<dim3(512), dim3(512), 0, stream>>>(
        feature, v_table, w_table, w0s, W0, b0, W1, b1, W2, b2, W3, b3,
        (float*)d_out);
}

// Round 12
// 44.431 us; speedup vs baseline: 1.2816x; 1.2816x over previous
//
#include <hip/hip_runtime.h>
#include <hip/hip_bf16.h>

#define NF 39
#define NK 64
#define NROW (NF * NK)   // 2496

__device__ __forceinline__ float bf_lo(unsigned u) { return __uint_as_float(u << 16); }
__device__ __forceinline__ float bf_hi(unsigned u) { return __uint_as_float(u & 0xffff0000u); }

__device__ __forceinline__ unsigned f2bf(float f) {
    unsigned u = __float_as_uint(f);
    return (u + 0x7fffu + ((u >> 16) & 1u)) >> 16;   // RNE
}

__global__ __launch_bounds__(512, 2)
void deepfm_kernel(const int* __restrict__ feature,
                   const float* __restrict__ v_table,
                   const float* __restrict__ w_table,
                   const float* __restrict__ w0s,
                   const float* __restrict__ W0,
                   const float* __restrict__ b0,
                   const float* __restrict__ W1,
                   const float* __restrict__ b1,
                   const float* __restrict__ W2,
                   const float* __restrict__ b2,
                   const float* __restrict__ W3,
                   const float* __restrict__ b3,
                   float* __restrict__ out)
{
    // W0 as packed bf16 pairs, [jp][row]: row = f*64+k. Lane reads 4 consecutive
    // rows (its k-quad) as one ds_read_b128 -> conflict-free (16 distinct 16B
    // addrs spanning all banks 2-way + 3 duplicate groups broadcast).
    __shared__ unsigned w0_lds[5 * NROW];   // 49920 B

    for (int i = threadIdx.x; i < NROW; i += 512) {
        #pragma unroll
        for (int jp = 0; jp < 5; ++jp) {
            unsigned lo = f2bf(W0[i * 10 + 2 * jp]);
            unsigned hi = f2bf(W0[i * 10 + 2 * jp + 1]);
            w0_lds[jp * NROW + i] = lo | (hi << 16);
        }
    }
    __syncthreads();

    const int lane = threadIdx.x & 63;
    const int wave = threadIdx.x >> 6;            // 0..7
    const int s0   = blockIdx.x * 32 + wave * 4;  // 4 samples per wave
    const int sg   = lane >> 4;                   // which sample (0..3)
    const int kq   = lane & 15;                   // k-quad: lane owns k = kq*4..kq*4+3

    const int* fptr = feature + (size_t)(s0 + sg) * NF;   // per-lane, loop-invariant

    float h0p[4][10];                 // [k-slot][j] partial DNN layer-0
    float sv[4], sq[4];
    float lin = 0.f;                  // full per-sample sum, identical within group
    #pragma unroll
    for (int i = 0; i < 4; ++i) {
        sv[i] = 0.f; sq[i] = 0.f;
        #pragma unroll
        for (int j = 0; j < 10; ++j) h0p[i][j] = 0.f;
    }

    #pragma unroll 2
    for (int f = 0; f < NF; ++f) {
        const int idx = fptr[f];                        // 16-lane dup, HW-merged
        lin += w_table[idx];                            // 4B gather, cache-resident
        // one wave-instruction fetches 4 full 256B rows (1KB in flight per instr)
        const float4 v4 = ((const float4*)(v_table + ((size_t)(unsigned)idx << 6)))[kq];
        const float vv[4] = { v4.x, v4.y, v4.z, v4.w };
        #pragma unroll
        for (int i = 0; i < 4; ++i) {
            sv[i] += vv[i];
            sq[i]  = fmaf(vv[i], vv[i], sq[i]);
        }
        #pragma unroll
        for (int jp = 0; jp < 5; ++jp) {
            const uint4 u = *(const uint4*)&w0_lds[jp * NROW + f * NK + kq * 4];
            h0p[0][2*jp]   = fmaf(vv[0], bf_lo(u.x), h0p[0][2*jp]);
            h0p[0][2*jp+1] = fmaf(vv[0], bf_hi(u.x), h0p[0][2*jp+1]);
            h0p[1][2*jp]   = fmaf(vv[1], bf_lo(u.y), h0p[1][2*jp]);
            h0p[1][2*jp+1] = fmaf(vv[1], bf_hi(u.y), h0p[1][2*jp+1]);
            h0p[2][2*jp]   = fmaf(vv[2], bf_lo(u.z), h0p[2][2*jp]);
            h0p[2][2*jp+1] = fmaf(vv[2], bf_hi(u.z), h0p[2][2*jp+1]);
            h0p[3][2*jp]   = fmaf(vv[3], bf_lo(u.w), h0p[3][2*jp]);
            h0p[3][2*jp+1] = fmaf(vv[3], bf_hi(u.w), h0p[3][2*jp+1]);
        }
    }

    // fold k-slots, then 4-step butterfly across the 16-lane group
    float t = 0.f;
    #pragma unroll
    for (int i = 0; i < 4; ++i) t += fmaf(sv[i], sv[i], -sq[i]);
    float hj[10];
    #pragma unroll
    for (int j = 0; j < 10; ++j)
        hj[j] = (h0p[0][j] + h0p[1][j]) + (h0p[2][j] + h0p[3][j]);
    #pragma unroll
    for (int m = 1; m < 16; m <<= 1) {
        t += __shfl_xor(t, m, 64);
        #pragma unroll
        for (int j = 0; j < 10; ++j)
            hj[j] += __shfl_xor(hj[j], m, 64);
    }

    // tiny MLP tail (values uniform within group; computed redundantly)
    const float w0v = w0s[0];
    float h0v[10];
    #pragma unroll
    for (int j = 0; j < 10; ++j) h0v[j] = fmaxf(hj[j] + b0[j], 0.f);
    float h1[5];
    #pragma unroll
    for (int p = 0; p < 5; ++p) {
        float a = b1[p];
        #pragma unroll
        for (int j = 0; j < 10; ++j) a = fmaf(h0v[j], W1[j * 5 + p], a);
        h1[p] = fmaxf(a, 0.f);
    }
    float h2[3];
    #pragma unroll
    for (int q = 0; q < 3; ++q) {
        float a = b2[q];
        #pragma unroll
        for (int p = 0; p < 5; ++p) a = fmaf(h1[p], W2[p * 3 + q], a);
        h2[q] = fmaxf(a, 0.f);
    }
    float dnn = b3[0];
    #pragma unroll
    for (int q = 0; q < 3; ++q) dnn = fmaf(h2[q], W3[q], dnn);

    if (kq == 0) out[s0 + sg] = 0.5f * t + lin + w0v + dnn;
}

extern "C" void kernel_launch(void* const* d_in, const int* in_sizes, int n_in,
                              void* d_out, int out_size, void* d_ws, size_t ws_size,
                              hipStream_t stream) {
    const int*   feature = (const int*)  d_in[0];
    const float* v_table = (const float*)d_in[1];
    const float* w_table = (const float*)d_in[2];
    const float* w0s     = (const float*)d_in[3];
    const float* W0      = (const float*)d_in[4];
    const float* b0      = (const float*)d_in[5];
    const float* W1      = (const float*)d_in[6];
    const float* b1      = (const float*)d_in[7];
    const float* W2      = (const float*)d_in[8];
    const float* b2      = (const float*)d_in[9];
    const float* W3      = (const float*)d_in[10];
    const float* b3      = (const float*)d_in[11];

    deepfm_kernel<<<dim3(512), dim3(512), 0, stream>>>(
        feature, v_table, w_table, w0s, W0, b0, W1, b1, W2, b2, W3, b3,
        (float*)d_out);
}